// Round 3
// baseline (689.251 us; speedup 1.0000x reference)
//
#include <hip/hip_runtime.h>
#include <hip/hip_bf16.h>
#include <math.h>

// Problem constants (fixed shapes from reference setup_inputs)
#define NS   32      // batch
#define TS   1024    // time steps
#define KIN  2048    // INPUT_SIZE
#define RED  128     // REDUCED
#define HID  32      // HIDDEN
#define G3   96      // 3*HIDDEN
#define SEQ  8       // x.shape[1] — x data itself is never used

#define GX_FLOATS (NS * TS * G3)   // 3,145,728
#define W_ELEMS   (G3 * KIN)       // 196,608 bf16 elements per buffer

typedef __attribute__((ext_vector_type(8))) short  short8;   // 8 bf16 (4 VGPRs)
typedef __attribute__((ext_vector_type(4))) float  floatx4;  // MFMA accumulator
typedef __attribute__((ext_vector_type(2))) float  floatx2;
typedef __attribute__((ext_vector_type(2))) unsigned int uint2v;

// fea_len may arrive as int32 or int64. int64 little-endian with values
// < 2^31 => odd int32 words are all zero.
__device__ __forceinline__ int load_len(const int* __restrict__ p, int n) {
    bool is64 = (p[1] == 0) && (p[3] == 0) && (p[5] == 0) && (p[7] == 0);
    if (is64) return (int)((const long long*)p)[n];
    return p[n];
}

__device__ __forceinline__ float fsig(float x) {
    // rcp is ~1ulp; fine for gate values in (0,1)
    return __builtin_amdgcn_rcpf(1.0f + __expf(-x));
}
__device__ __forceinline__ float ftanh(float x) {
    float ax = fabsf(x);
    float e  = __expf(-2.0f * ax);
    float r  = (1.0f - e) * __builtin_amdgcn_rcpf(1.0f + e);
    return copysignf(r, x);
}

// scalar fp32 -> bf16 (RNE) and back (exact)
__device__ __forceinline__ unsigned short f2bf(float x) {
    unsigned u = __float_as_uint(x);
    unsigned r = u + 0x7fffu + ((u >> 16) & 1u);
    return (unsigned short)(r >> 16);
}
__device__ __forceinline__ float bfu2f(unsigned short u) {
    return __uint_as_float(((unsigned)u) << 16);
}

// ---- permlane swaps: builtin if available, raw instruction otherwise ------
__device__ __forceinline__ void swap16(unsigned& a, unsigned& b) {
#if __has_builtin(__builtin_amdgcn_permlane16_swap)
    uint2v r = __builtin_amdgcn_permlane16_swap(a, b, false, false);
    a = r.x; b = r.y;
#else
    asm("v_permlane16_swap_b32 %0, %1" : "+v"(a), "+v"(b));
#endif
}
__device__ __forceinline__ void swap32(unsigned& a, unsigned& b) {
#if __has_builtin(__builtin_amdgcn_permlane32_swap)
    uint2v r = __builtin_amdgcn_permlane32_swap(a, b, false, false);
    a = r.x; b = r.y;
#else
    asm("v_permlane32_swap_b32 %0, %1" : "+v"(a), "+v"(b));
#endif
}

// sum over lane pairs (l, l^32): direction-independent (a+b covers both)
__device__ __forceinline__ float xor32sum(float x) {
    unsigned a = __float_as_uint(x), b = a;
    swap32(a, b);
    return __uint_as_float(a) + __uint_as_float(b);
}

#define DPPM(srcv, ctrl) __uint_as_float((unsigned)__builtin_amdgcn_update_dpp( \
        (int)__float_as_uint(srcv), (int)__float_as_uint(srcv), (ctrl), 0xF, 0xF, false))

// packed hi/lo split of 8 floats -> two bf16x8 fragments
__device__ __forceinline__ void cvt_hilo(const float* f, short8& hi, short8& lo) {
    #pragma unroll
    for (int p = 0; p < 4; ++p) {
        float2 fv = make_float2(f[2*p], f[2*p+1]);
        union { __hip_bfloat162 b2; unsigned short us[2]; } H, L;
        H.b2 = __float22bfloat162_rn(fv);
        float2 hb = __bfloat1622float2(H.b2);
        L.b2 = __float22bfloat162_rn(make_float2(fv.x - hb.x, fv.y - hb.y));
        hi[2*p] = (short)H.us[0]; hi[2*p+1] = (short)H.us[1];
        lo[2*p] = (short)L.us[0]; lo[2*p+1] = (short)L.us[1];
    }
}

// ---------------------------------------------------------------------------
// K1: W_comb = W_ih @ W_ann (96 x 2048), emitted as bf16 hi/lo pair;
//     b_comb[j] = b_ih[j] + W_ih[j]·b_ann.
// ---------------------------------------------------------------------------
__global__ __launch_bounds__(256) void k_prep(
        const float* __restrict__ W_ann, const float* __restrict__ b_ann,
        const float* __restrict__ W_ih,  const float* __restrict__ b_ih,
        unsigned short* __restrict__ Whi, unsigned short* __restrict__ Wlo,
        float* __restrict__ b_comb) {
    if (blockIdx.x == 768) {
        int j = threadIdx.x;
        if (j < G3) {
            float acc = b_ih[j];
            #pragma unroll 8
            for (int m = 0; m < RED; ++m) acc += W_ih[j * RED + m] * b_ann[m];
            b_comb[j] = acc;
        }
        return;
    }
    int id = blockIdx.x * 256 + threadIdx.x;   // 0 .. 196607
    int j = id >> 11;          // /2048
    int k = id & (KIN - 1);
    float acc = 0.0f;
    #pragma unroll 8
    for (int m = 0; m < RED; ++m) acc += W_ih[j * RED + m] * W_ann[m * KIN + k];
    unsigned short h = f2bf(acc);
    Whi[id] = h;
    Wlo[id] = f2bf(acc - bfu2f(h));
}

// ---------------------------------------------------------------------------
// K2: MFMA GEMM, no LDS / no barriers. gx[n][t][j] = fea[n][t][:]·Wc[j][:] + b_comb[j]
// computed as Ah·Bh + Ah·Bl + Al·Bh (bf16 hi/lo split, fp32 accumulate).
// Block: 256 thr = 4 waves; tile 128 t x 96 j; wave w owns rows [w*32, w*32+32).
// mfma_f32_16x16x32_bf16 layouts:
//   A: A[m=lane&15][k=(lane>>4)*8+i]  -> 32 contiguous bytes of one fea row/lane
//   B: B[k=(lane>>4)*8+i][n=lane&15]  -> 16 contiguous bytes of one W row/lane
//   D: row=(lane>>4)*4+reg, col=lane&15
// ---------------------------------------------------------------------------
__global__ __launch_bounds__(256) void k_gemm(
        const float* __restrict__ fea, const int* __restrict__ flen,
        const unsigned short* __restrict__ Whi,
        const unsigned short* __restrict__ Wlo,
        const float* __restrict__ b_comb,
        float* __restrict__ gx) {
    const int n  = blockIdx.x;
    const int t0 = blockIdx.y * 128;
    const int L  = load_len(flen, n) + SEQ;
    if (t0 >= L) return;   // scan never reads gx at t >= L

    const int tid  = threadIdx.x;
    const int w    = tid >> 6;      // wave 0..3
    const int ln   = tid & 63;
    const int mr   = ln & 15;       // row-within-frag / col-within-frag
    const int quad = ln >> 4;       // 0..3

    // A row base offsets (elements) for the wave's two 16-row M-frags
    const size_t arow0 = ((size_t)(n * TS + t0 + w * 32 + mr)) * KIN + quad * 8;
    const size_t arow1 = arow0 + (size_t)16 * KIN;
    // B row offsets per N-frag
    int boff[6];
    #pragma unroll
    for (int nf = 0; nf < 6; ++nf) boff[nf] = (nf * 16 + mr) * KIN + quad * 8;

    floatx4 acc[2][6];
    #pragma unroll
    for (int mf = 0; mf < 2; ++mf)
        #pragma unroll
        for (int nf = 0; nf < 6; ++nf) acc[mf][nf] = (floatx4){0.f, 0.f, 0.f, 0.f};

    #pragma unroll 1
    for (int c = 0; c < KIN / 64; ++c) {
        #pragma unroll
        for (int ks = 0; ks < 2; ++ks) {
            const int ko = c * 64 + ks * 32;
            float fa[8], fb[8];
            {
                float4 a0 = *(const float4*)(fea + arow0 + ko);
                float4 a1 = *(const float4*)(fea + arow0 + ko + 4);
                float4 b0 = *(const float4*)(fea + arow1 + ko);
                float4 b1 = *(const float4*)(fea + arow1 + ko + 4);
                fa[0]=a0.x; fa[1]=a0.y; fa[2]=a0.z; fa[3]=a0.w;
                fa[4]=a1.x; fa[5]=a1.y; fa[6]=a1.z; fa[7]=a1.w;
                fb[0]=b0.x; fb[1]=b0.y; fb[2]=b0.z; fb[3]=b0.w;
                fb[4]=b1.x; fb[5]=b1.y; fb[6]=b1.z; fb[7]=b1.w;
            }
            short8 ah0, al0, ah1, al1;
            cvt_hilo(fa, ah0, al0);
            cvt_hilo(fb, ah1, al1);
            #pragma unroll
            for (int nf = 0; nf < 6; ++nf) {
                short8 bh = *(const short8*)(Whi + boff[nf] + ko);
                short8 bl = *(const short8*)(Wlo + boff[nf] + ko);
                acc[0][nf] = __builtin_amdgcn_mfma_f32_16x16x32_bf16(ah0, bh, acc[0][nf], 0, 0, 0);
                acc[0][nf] = __builtin_amdgcn_mfma_f32_16x16x32_bf16(ah0, bl, acc[0][nf], 0, 0, 0);
                acc[0][nf] = __builtin_amdgcn_mfma_f32_16x16x32_bf16(al0, bh, acc[0][nf], 0, 0, 0);
                acc[1][nf] = __builtin_amdgcn_mfma_f32_16x16x32_bf16(ah1, bh, acc[1][nf], 0, 0, 0);
                acc[1][nf] = __builtin_amdgcn_mfma_f32_16x16x32_bf16(ah1, bl, acc[1][nf], 0, 0, 0);
                acc[1][nf] = __builtin_amdgcn_mfma_f32_16x16x32_bf16(al1, bh, acc[1][nf], 0, 0, 0);
            }
        }
    }

    // epilogue: D row=(lane>>4)*4+r, col=lane&15
    #pragma unroll
    for (int mf = 0; mf < 2; ++mf) {
        const int tbase = t0 + w * 32 + mf * 16 + quad * 4;
        #pragma unroll
        for (int nf = 0; nf < 6; ++nf) {
            const float bc = b_comb[nf * 16 + mr];
            float* gp = gx + ((size_t)(n * TS + tbase)) * G3 + nf * 16 + mr;
            #pragma unroll
            for (int r = 0; r < 4; ++r)
                gp[(size_t)r * G3] = acc[mf][nf][r] + bc;
        }
    }
}

// ---------------------------------------------------------------------------
// K3: GRU scan + q + masked mean. One wave per sample.
//
// Lane mapping: j = lane&31 (hidden unit / gate row), kh = lane>>5 (K-half).
// Invariant: lanes j and 32+j always hold identical h streams, so all
// cross-lane traffic is VALU-speed (no ds_bpermute on the critical path):
//   - split-K reduce: v_permlane32_swap (sum of both outputs = pairwise sum,
//     direction-independent)
//   - h redistribute: v_permlane16_swap yields {h[l15], h[16+l15]} in a
//     hardware-defined order; a one-time lane-index probe resolves the
//     direction into a single precomputed cndmask condition. A 15-mov DPP
//     butterfly (quad_perm xor1/xor2, row_half_mirror=xor7, row_mirror=xor15)
//     then fans out all 16 h's per half. Weights are gathered once with the
//     matching per-lane XOR permutation.
// Dots are float2 packed (v_pk_fma_f32-eligible) with depth-8 chains.
//
// amdgpu_waves_per_eu(1,1): this kernel runs 32 blocks x 1 wave on 256 CUs —
// occupancy is irrelevant. Pinning max waves/EU to 1 unlocks the full VGPR
// budget so the 48 weight regs + 24-reg prefetch ring + 16-reg hv butterfly
// stay register-resident (round 2 showed VGPR_Count=56 < live set => LLVM
// was re-fetching loop-invariant weights from memory every step).
// ---------------------------------------------------------------------------
__global__ __launch_bounds__(64)
__attribute__((amdgpu_waves_per_eu(1, 1)))
void k_scan(
        const float* __restrict__ gx, const int* __restrict__ flen,
        const float* __restrict__ W_hh, const float* __restrict__ b_hh,
        const float* __restrict__ W_q,  const float* __restrict__ b_q,
        float* __restrict__ out) {
    const int n    = blockIdx.x;
    const int lane = threadIdx.x;
    const int j    = lane & 31;   // hidden unit / gate row
    const int kh   = lane >> 5;   // K-half
    const int l15  = lane & 15;
    const int L    = load_len(flen, n) + SEQ;   // L >= 8 always

    // butterfly xor-mask order: hv reg m holds h[kh*16 + (l15 ^ MT[m])]
    const int MT[16] = {0,1,2,3, 7,6,5,4, 15,14,13,12, 8,9,10,11};

    // per-lane recurrent weights, permuted to match the butterfly layout
    floatx2 wr2[8], wz2[8], wn2[8];
    #pragma unroll
    for (int k2 = 0; k2 < 8; ++k2) {
        const int ka = kh * 16 + (l15 ^ MT[2*k2]);
        const int kb = kh * 16 + (l15 ^ MT[2*k2+1]);
        wr2[k2].x = W_hh[(size_t)(j)      * HID + ka];
        wr2[k2].y = W_hh[(size_t)(j)      * HID + kb];
        wz2[k2].x = W_hh[(size_t)(32 + j) * HID + ka];
        wz2[k2].y = W_hh[(size_t)(32 + j) * HID + kb];
        wn2[k2].x = W_hh[(size_t)(64 + j) * HID + ka];
        wn2[k2].y = W_hh[(size_t)(64 + j) * HID + kb];
    }
    const float br = b_hh[j], bz = b_hh[32 + j], bn = b_hh[64 + j];
    const float wq = W_q[j];
    const float bq = b_q[0];
    const bool  hi = (lane >= 32);

    // one-time probe: which output of permlane16_swap holds the bit4-cleared
    // lane's value? (resolves ISA direction ambiguity at runtime, ~5 instrs)
    bool selY;   // true => take .y for this lane's half, false => take .x
    {
        unsigned a = (unsigned)lane, b = (unsigned)lane;
        swap16(a, b);
        const bool dirA = ((a & 16u) == 0u);   // uniform across lanes
        selY = dirA ? hi : !hi;
    }

    const float* gbase = gx + (size_t)n * TS * G3;

    // depth-8 register prefetch ring; both halves load identical addresses,
    // so x-parts are added per-lane AFTER the cross-half reduce (no select).
    float rg[8][3];
    #pragma unroll
    for (int i = 0; i < 8; ++i) {
        const float* p = gbase + (size_t)i * G3;
        rg[i][0] = p[j]; rg[i][1] = p[32 + j]; rg[i][2] = p[64 + j];
    }

    floatx2 hv2[8];
    #pragma unroll
    for (int k2 = 0; k2 < 8; ++k2) hv2[k2] = (floatx2){0.f, 0.f};
    float h = 0.0f, qacc = 0.0f;

    for (int tb = 0; tb < L; tb += 8) {
        #pragma unroll
        for (int i = 0; i < 8; ++i) {
            const int t = tb + i;
            const float xr = rg[i][0], xz = rg[i][1], xn = rg[i][2];
            // refill slot i for t+8 (clip; beyond-L garbage never consumed)
            {
                int tl = t + 8; if (tl > TS - 1) tl = TS - 1;
                const float* p = gbase + (size_t)tl * G3;
                rg[i][0] = p[j]; rg[i][1] = p[32 + j]; rg[i][2] = p[64 + j];
            }

            // packed half-K dots (depth-8 chains on float2 lanes)
            floatx2 ar = (floatx2){0.f, 0.f};
            floatx2 az = (floatx2){0.f, 0.f};
            floatx2 an = (floatx2){0.f, 0.f};
            #pragma unroll
            for (int k2 = 0; k2 < 8; ++k2) {
                ar += wr2[k2] * hv2[k2];
                az += wz2[k2] * hv2[k2];
                an += wn2[k2] * hv2[k2];
            }
            float dr = xor32sum(ar.x + ar.y);
            float dz = xor32sum(az.x + az.y);
            float dn = xor32sum(an.x + an.y);

            float r    = fsig(xr + dr + br);
            float z    = fsig(xz + dz + bz);
            float nng  = ftanh(xn + r * (dn + bn));
            float hnew = nng + z * (h - nng);
            if (t < L) {                   // wave-uniform predicate
                h = hnew;
                qacc += wq * hnew;
            }

            // redistribute h -> hv2 (all VALU: permlane16_swap + DPP butterfly)
            {
                unsigned pa = __float_as_uint(h), pb = pa;
                swap16(pa, pb);
                // {pa,pb} = {h[l15], h[16+l15]} in hw-defined order; selY picks
                hv2[0].x = selY ? __uint_as_float(pb) : __uint_as_float(pa);
                hv2[0].y = DPPM(hv2[0].x, 0xB1);         // quad_perm [1,0,3,2] : xor1
                hv2[1].x = DPPM(hv2[0].x, 0x4E);         // quad_perm [2,3,0,1] : xor2
                hv2[1].y = DPPM(hv2[0].y, 0x4E);         // xor3
                hv2[2].x = DPPM(hv2[0].x, 0x141);        // row_half_mirror : xor7
                hv2[2].y = DPPM(hv2[0].y, 0x141);        // xor6
                hv2[3].x = DPPM(hv2[1].x, 0x141);        // xor5
                hv2[3].y = DPPM(hv2[1].y, 0x141);        // xor4
                hv2[4].x = DPPM(hv2[0].x, 0x140);        // row_mirror : xor15
                hv2[4].y = DPPM(hv2[0].y, 0x140);        // xor14
                hv2[5].x = DPPM(hv2[1].x, 0x140);        // xor13
                hv2[5].y = DPPM(hv2[1].y, 0x140);        // xor12
                hv2[6].x = DPPM(hv2[2].x, 0x140);        // xor8
                hv2[6].y = DPPM(hv2[2].y, 0x140);        // xor9
                hv2[7].x = DPPM(hv2[3].x, 0x140);        // xor10
                hv2[7].y = DPPM(hv2[3].y, 0x140);        // xor11
            }
        }
    }

    // every j counted twice (kh=0 and kh=1 lanes hold identical streams)
    #pragma unroll
    for (int off = 32; off > 0; off >>= 1) qacc += __shfl_xor(qacc, off, 64);
    if (lane == 0) out[n] = qacc * 0.5f / (float)L + bq;
}

// ---------------------------------------------------------------------------
extern "C" void kernel_launch(void* const* d_in, const int* in_sizes, int n_in,
                              void* d_out, int out_size, void* d_ws, size_t ws_size,
                              hipStream_t stream) {
    // setup_inputs order: x, fea, fea_len, W_ann, b_ann, W_ih, W_hh, b_ih, b_hh, W_q, b_q
    const float* fea   = (const float*)d_in[1];
    const int*   flen  = (const int*)  d_in[2];
    const float* W_ann = (const float*)d_in[3];
    const float* b_ann = (const float*)d_in[4];
    const float* W_ih  = (const float*)d_in[5];
    const float* W_hh  = (const float*)d_in[6];
    const float* b_ih  = (const float*)d_in[7];
    const float* b_hh  = (const float*)d_in[8];
    const float* W_q   = (const float*)d_in[9];
    const float* b_q   = (const float*)d_in[10];
    float* out = (float*)d_out;

    // ws layout: gx fp32 | Whi bf16 | Wlo bf16 | b_comb   (~13.4 MB total)
    float*          ws_f   = (float*)d_ws;
    float*          gx     = ws_f;
    unsigned short* Whi    = (unsigned short*)(ws_f + GX_FLOATS);
    unsigned short* Wlo    = Whi + W_ELEMS;
    float*          b_comb = (float*)(Wlo + W_ELEMS);

    k_prep<<<769, 256, 0, stream>>>(W_ann, b_ann, W_ih, b_ih, Whi, Wlo, b_comb);

    dim3 g2(NS, TS / 128);               // (32 samples, 8 t-tiles of 128)
    k_gemm<<<g2, 256, 0, stream>>>(fea, flen, Whi, Wlo, b_comb, gx);

    k_scan<<<NS, 64, 0, stream>>>(gx, flen, W_hh, b_hh, W_q, b_q, out);
}

// Round 4
// 664.709 us; speedup vs baseline: 1.0369x; 1.0369x over previous
//
#include <hip/hip_runtime.h>
#include <hip/hip_bf16.h>
#include <math.h>

// Problem constants (fixed shapes from reference setup_inputs)
#define NS   32      // batch
#define TS   1024    // time steps
#define KIN  2048    // INPUT_SIZE
#define RED  128     // REDUCED
#define HID  32      // HIDDEN
#define G3   96      // 3*HIDDEN
#define SEQ  8       // x.shape[1] — x data itself is never used

#define GX_FLOATS (NS * TS * G3)   // 3,145,728
#define W_ELEMS   (G3 * KIN)       // 196,608 bf16 elements per buffer

typedef __attribute__((ext_vector_type(8))) short  short8;   // 8 bf16 (4 VGPRs)
typedef __attribute__((ext_vector_type(4))) float  floatx4;  // MFMA accumulator
typedef __attribute__((ext_vector_type(2))) float  floatx2;
typedef __attribute__((ext_vector_type(2))) unsigned int uint2v;

// fea_len may arrive as int32 or int64. int64 little-endian with values
// < 2^31 => odd int32 words are all zero.
__device__ __forceinline__ int load_len(const int* __restrict__ p, int n) {
    bool is64 = (p[1] == 0) && (p[3] == 0) && (p[5] == 0) && (p[7] == 0);
    if (is64) return (int)((const long long*)p)[n];
    return p[n];
}

// scalar fp32 -> bf16 (RNE) and back (exact)
__device__ __forceinline__ unsigned short f2bf(float x) {
    unsigned u = __float_as_uint(x);
    unsigned r = u + 0x7fffu + ((u >> 16) & 1u);
    return (unsigned short)(r >> 16);
}
__device__ __forceinline__ float bfu2f(unsigned short u) {
    return __uint_as_float(((unsigned)u) << 16);
}

// v_exp_f32 computes 2^x; expose it directly (weights are pre-scaled by log2e)
__device__ __forceinline__ float fexp2(float x) {
#if __has_builtin(__builtin_amdgcn_exp2f)
    return __builtin_amdgcn_exp2f(x);
#else
    return exp2f(x);
#endif
}

// ---- permlane swaps: builtin if available, raw instruction otherwise ------
__device__ __forceinline__ void swap16(unsigned& a, unsigned& b) {
#if __has_builtin(__builtin_amdgcn_permlane16_swap)
    uint2v r = __builtin_amdgcn_permlane16_swap(a, b, false, false);
    a = r.x; b = r.y;
#else
    asm("v_permlane16_swap_b32 %0, %1" : "+v"(a), "+v"(b));
#endif
}
__device__ __forceinline__ void swap32(unsigned& a, unsigned& b) {
#if __has_builtin(__builtin_amdgcn_permlane32_swap)
    uint2v r = __builtin_amdgcn_permlane32_swap(a, b, false, false);
    a = r.x; b = r.y;
#else
    asm("v_permlane32_swap_b32 %0, %1" : "+v"(a), "+v"(b));
#endif
}

// sum over lane pairs (l, l^32): direction-independent (a+b covers both)
__device__ __forceinline__ float xor32sum(float x) {
    unsigned a = __float_as_uint(x), b = a;
    swap32(a, b);
    return __uint_as_float(a) + __uint_as_float(b);
}

#define DPPM(srcv, ctrl) __uint_as_float((unsigned)__builtin_amdgcn_update_dpp( \
        (int)__float_as_uint(srcv), (int)__float_as_uint(srcv), (ctrl), 0xF, 0xF, false))

// packed hi/lo split of 8 floats -> two bf16x8 fragments
__device__ __forceinline__ void cvt_hilo(const float* f, short8& hi, short8& lo) {
    #pragma unroll
    for (int p = 0; p < 4; ++p) {
        float2 fv = make_float2(f[2*p], f[2*p+1]);
        union { __hip_bfloat162 b2; unsigned short us[2]; } H, L;
        H.b2 = __float22bfloat162_rn(fv);
        float2 hb = __bfloat1622float2(H.b2);
        L.b2 = __float22bfloat162_rn(make_float2(fv.x - hb.x, fv.y - hb.y));
        hi[2*p] = (short)H.us[0]; hi[2*p+1] = (short)H.us[1];
        lo[2*p] = (short)L.us[0]; lo[2*p+1] = (short)L.us[1];
    }
}

// ---------------------------------------------------------------------------
// K1: W_comb = W_ih @ W_ann (96 x 2048), emitted as bf16 hi/lo pair;
//     b_comb[j] = b_ih[j] + W_ih[j]·b_ann.
// ---------------------------------------------------------------------------
__global__ __launch_bounds__(256) void k_prep(
        const float* __restrict__ W_ann, const float* __restrict__ b_ann,
        const float* __restrict__ W_ih,  const float* __restrict__ b_ih,
        unsigned short* __restrict__ Whi, unsigned short* __restrict__ Wlo,
        float* __restrict__ b_comb) {
    if (blockIdx.x == 768) {
        int j = threadIdx.x;
        if (j < G3) {
            float acc = b_ih[j];
            #pragma unroll 8
            for (int m = 0; m < RED; ++m) acc += W_ih[j * RED + m] * b_ann[m];
            b_comb[j] = acc;
        }
        return;
    }
    int id = blockIdx.x * 256 + threadIdx.x;   // 0 .. 196607
    int j = id >> 11;          // /2048
    int k = id & (KIN - 1);
    float acc = 0.0f;
    #pragma unroll 8
    for (int m = 0; m < RED; ++m) acc += W_ih[j * RED + m] * W_ann[m * KIN + k];
    unsigned short h = f2bf(acc);
    Whi[id] = h;
    Wlo[id] = f2bf(acc - bfu2f(h));
}

// ---------------------------------------------------------------------------
// K2: MFMA GEMM, no LDS / no barriers. gx[n][t][j] = fea[n][t][:]·Wc[j][:] + b_comb[j]
// computed as Ah·Bh + Ah·Bl + Al·Bh (bf16 hi/lo split, fp32 accumulate).
// Block: 256 thr = 4 waves; tile 128 t x 96 j; wave w owns rows [w*32, w*32+32).
// mfma_f32_16x16x32_bf16 layouts:
//   A: A[m=lane&15][k=(lane>>4)*8+i]  -> 32 contiguous bytes of one fea row/lane
//   B: B[k=(lane>>4)*8+i][n=lane&15]  -> 16 contiguous bytes of one W row/lane
//   D: row=(lane>>4)*4+reg, col=lane&15
// ---------------------------------------------------------------------------
__global__ __launch_bounds__(256) void k_gemm(
        const float* __restrict__ fea, const int* __restrict__ flen,
        const unsigned short* __restrict__ Whi,
        const unsigned short* __restrict__ Wlo,
        const float* __restrict__ b_comb,
        float* __restrict__ gx) {
    const int n  = blockIdx.x;
    const int t0 = blockIdx.y * 128;
    const int L  = load_len(flen, n) + SEQ;
    if (t0 >= L) return;   // scan never reads gx at t >= L

    const int tid  = threadIdx.x;
    const int w    = tid >> 6;      // wave 0..3
    const int ln   = tid & 63;
    const int mr   = ln & 15;       // row-within-frag / col-within-frag
    const int quad = ln >> 4;       // 0..3

    // A row base offsets (elements) for the wave's two 16-row M-frags
    const size_t arow0 = ((size_t)(n * TS + t0 + w * 32 + mr)) * KIN + quad * 8;
    const size_t arow1 = arow0 + (size_t)16 * KIN;
    // B row offsets per N-frag
    int boff[6];
    #pragma unroll
    for (int nf = 0; nf < 6; ++nf) boff[nf] = (nf * 16 + mr) * KIN + quad * 8;

    floatx4 acc[2][6];
    #pragma unroll
    for (int mf = 0; mf < 2; ++mf)
        #pragma unroll
        for (int nf = 0; nf < 6; ++nf) acc[mf][nf] = (floatx4){0.f, 0.f, 0.f, 0.f};

    #pragma unroll 1
    for (int c = 0; c < KIN / 64; ++c) {
        #pragma unroll
        for (int ks = 0; ks < 2; ++ks) {
            const int ko = c * 64 + ks * 32;
            float fa[8], fb[8];
            {
                float4 a0 = *(const float4*)(fea + arow0 + ko);
                float4 a1 = *(const float4*)(fea + arow0 + ko + 4);
                float4 b0 = *(const float4*)(fea + arow1 + ko);
                float4 b1 = *(const float4*)(fea + arow1 + ko + 4);
                fa[0]=a0.x; fa[1]=a0.y; fa[2]=a0.z; fa[3]=a0.w;
                fa[4]=a1.x; fa[5]=a1.y; fa[6]=a1.z; fa[7]=a1.w;
                fb[0]=b0.x; fb[1]=b0.y; fb[2]=b0.z; fb[3]=b0.w;
                fb[4]=b1.x; fb[5]=b1.y; fb[6]=b1.z; fb[7]=b1.w;
            }
            short8 ah0, al0, ah1, al1;
            cvt_hilo(fa, ah0, al0);
            cvt_hilo(fb, ah1, al1);
            #pragma unroll
            for (int nf = 0; nf < 6; ++nf) {
                short8 bh = *(const short8*)(Whi + boff[nf] + ko);
                short8 bl = *(const short8*)(Wlo + boff[nf] + ko);
                acc[0][nf] = __builtin_amdgcn_mfma_f32_16x16x32_bf16(ah0, bh, acc[0][nf], 0, 0, 0);
                acc[0][nf] = __builtin_amdgcn_mfma_f32_16x16x32_bf16(ah0, bl, acc[0][nf], 0, 0, 0);
                acc[0][nf] = __builtin_amdgcn_mfma_f32_16x16x32_bf16(al0, bh, acc[0][nf], 0, 0, 0);
                acc[1][nf] = __builtin_amdgcn_mfma_f32_16x16x32_bf16(ah1, bh, acc[1][nf], 0, 0, 0);
                acc[1][nf] = __builtin_amdgcn_mfma_f32_16x16x32_bf16(ah1, bl, acc[1][nf], 0, 0, 0);
                acc[1][nf] = __builtin_amdgcn_mfma_f32_16x16x32_bf16(al1, bh, acc[1][nf], 0, 0, 0);
            }
        }
    }

    // epilogue: D row=(lane>>4)*4+r, col=lane&15
    #pragma unroll
    for (int mf = 0; mf < 2; ++mf) {
        const int tbase = t0 + w * 32 + mf * 16 + quad * 4;
        #pragma unroll
        for (int nf = 0; nf < 6; ++nf) {
            const float bc = b_comb[nf * 16 + mr];
            float* gp = gx + ((size_t)(n * TS + tbase)) * G3 + nf * 16 + mr;
            #pragma unroll
            for (int r = 0; r < 4; ++r)
                gp[(size_t)r * G3] = acc[mf][nf][r] + bc;
        }
    }
}

// ---------------------------------------------------------------------------
// K3: GRU scan + q + masked mean. One wave per sample. LATENCY-BOUND on the
// serial h->h chain (round 3: 550 cy/step, 45% issue duty) — so everything
// below is about shortening the dependent chain, not instruction count:
//   - x-parts and biases folded into the dot-accumulator INIT (computable
//     off-chain from the 8-step-ahead prefetch ring)
//   - weights pre-scaled by -log2e (r,z) / +2log2e (n) so the reduce result
//     feeds v_exp_f32 (= 2^x) directly (no on-chain muls)
//   - tanh(y) = 1 - 2/(1+e^{2y}) — branch-free, no abs/copysign (args
//     bounded |y| ≲ 12; degrades gracefully to ±1 at inf)
//   - dot = two 4-deep chained pk_fma chains + merge (not one 8-deep)
//   - main loop runs floor(L/8)*8 steps predicate-free; tail block predicated
// Cross-lane traffic stays VALU-speed: permlane32_swap reduce, permlane16_swap
// + 15-mov DPP butterfly redistribute (weights gathered with matching XOR).
// amdgpu_waves_per_eu(1,1): 32 blocks x 1 wave on 256 CUs — occupancy is
// irrelevant; unlock the full VGPR budget (round 3: VGPR 56 -> 132).
// ---------------------------------------------------------------------------
__global__ __launch_bounds__(64)
__attribute__((amdgpu_waves_per_eu(1, 1)))
void k_scan(
        const float* __restrict__ gx, const int* __restrict__ flen,
        const float* __restrict__ W_hh, const float* __restrict__ b_hh,
        const float* __restrict__ W_q,  const float* __restrict__ b_q,
        float* __restrict__ out) {
    const int n    = blockIdx.x;
    const int lane = threadIdx.x;
    const int j    = lane & 31;   // hidden unit / gate row
    const int kh   = lane >> 5;   // K-half
    const int l15  = lane & 15;
    const int L    = load_len(flen, n) + SEQ;   // L >= 8 always

    const float LOG2E = 1.4426950408889634f;

    // butterfly xor-mask order: hv reg m holds h[kh*16 + (l15 ^ MT[m])]
    const int MT[16] = {0,1,2,3, 7,6,5,4, 15,14,13,12, 8,9,10,11};

    // per-lane recurrent weights, permuted to match the butterfly layout and
    // PRE-SCALED: r,z by -log2e (sigmoid via 2^s), n by +2log2e (tanh via 2^s)
    floatx2 wr2[8], wz2[8], wn2[8];
    #pragma unroll
    for (int k2 = 0; k2 < 8; ++k2) {
        const int ka = kh * 16 + (l15 ^ MT[2*k2]);
        const int kb = kh * 16 + (l15 ^ MT[2*k2+1]);
        wr2[k2].x = -LOG2E * W_hh[(size_t)(j)      * HID + ka];
        wr2[k2].y = -LOG2E * W_hh[(size_t)(j)      * HID + kb];
        wz2[k2].x = -LOG2E * W_hh[(size_t)(32 + j) * HID + ka];
        wz2[k2].y = -LOG2E * W_hh[(size_t)(32 + j) * HID + kb];
        wn2[k2].x = 2.0f * LOG2E * W_hh[(size_t)(64 + j) * HID + ka];
        wn2[k2].y = 2.0f * LOG2E * W_hh[(size_t)(64 + j) * HID + kb];
    }
    // bias folds (each K-half contributes half of the shared terms)
    const float mh  = -0.5f * LOG2E;               // per-half scale for x,b of r,z
    const float brm = mh * b_hh[j];
    const float bzm = mh * b_hh[32 + j];
    const float bnm = LOG2E * b_hh[64 + j];        // per-half: (2log2e*bn)/2
    const float xnf = 2.0f * LOG2E;
    const float wq  = W_q[j];
    const float bq  = b_q[0];
    const bool  hi  = (lane >= 32);

    // one-time probe: resolve permlane16_swap direction into one cndmask cond
    bool selY;
    {
        unsigned a = (unsigned)lane, b = (unsigned)lane;
        swap16(a, b);
        const bool dirA = ((a & 16u) == 0u);   // uniform across lanes
        selY = dirA ? hi : !hi;
    }

    const float* gbase = gx + (size_t)n * TS * G3;

    // depth-8 register prefetch ring; both halves load identical addresses.
    float rg[8][3];
    #pragma unroll
    for (int i = 0; i < 8; ++i) {
        const float* p = gbase + (size_t)i * G3;
        rg[i][0] = p[j]; rg[i][1] = p[32 + j]; rg[i][2] = p[64 + j];
    }

    floatx2 hv2[8];
    #pragma unroll
    for (int k2 = 0; k2 < 8; ++k2) hv2[k2] = (floatx2){0.f, 0.f};
    float h = 0.0f, qacc = 0.0f;

    // one GRU step: dots -> reduce -> gates -> h update -> butterfly
    #define GRU_STEP(XR, XZ, XN, DO_UPDATE)                                   \
    {                                                                         \
        floatx2 aA = (floatx2){__builtin_fmaf(mh, (XR), brm), 0.f};           \
        floatx2 zA = (floatx2){__builtin_fmaf(mh, (XZ), bzm), 0.f};           \
        floatx2 nA = (floatx2){bnm, 0.f};                                     \
        floatx2 aB = (floatx2){0.f, 0.f}, zB = aB, nB = aB;                   \
        const float xn2 = xnf * (XN);                                         \
        _Pragma("unroll")                                                     \
        for (int k2 = 0; k2 < 4; ++k2) {                                      \
            aA += wr2[k2] * hv2[k2];   aB += wr2[k2+4] * hv2[k2+4];           \
            zA += wz2[k2] * hv2[k2];   zB += wz2[k2+4] * hv2[k2+4];           \
            nA += wn2[k2] * hv2[k2];   nB += wn2[k2+4] * hv2[k2+4];           \
        }                                                                     \
        floatx2 av = aA + aB, zv = zA + zB, nv = nA + nB;                     \
        float sr   = xor32sum(av.x + av.y);                                   \
        float sz   = xor32sum(zv.x + zv.y);                                   \
        float dnb2 = xor32sum(nv.x + nv.y);                                   \
        float r    = __builtin_amdgcn_rcpf(1.0f + fexp2(sr));                 \
        float z    = __builtin_amdgcn_rcpf(1.0f + fexp2(sz));                 \
        float sn   = __builtin_fmaf(r, dnb2, xn2);                            \
        float u    = __builtin_amdgcn_rcpf(1.0f + fexp2(sn));                 \
        float nng  = __builtin_fmaf(-2.0f, u, 1.0f);                          \
        float hnew = __builtin_fmaf(z, h - nng, nng);                         \
        if (DO_UPDATE) {                                                      \
            h = hnew;                                                         \
            qacc = __builtin_fmaf(wq, hnew, qacc);                            \
        }                                                                     \
        {   /* redistribute h -> hv2 (permlane16_swap + DPP butterfly) */     \
            unsigned pa = __float_as_uint(h), pb = pa;                        \
            swap16(pa, pb);                                                   \
            hv2[0].x = selY ? __uint_as_float(pb) : __uint_as_float(pa);      \
            hv2[0].y = DPPM(hv2[0].x, 0xB1);     /* xor1  */                  \
            hv2[1].x = DPPM(hv2[0].x, 0x4E);     /* xor2  */                  \
            hv2[1].y = DPPM(hv2[0].y, 0x4E);     /* xor3  */                  \
            hv2[2].x = DPPM(hv2[0].x, 0x141);    /* xor7  */                  \
            hv2[2].y = DPPM(hv2[0].y, 0x141);    /* xor6  */                  \
            hv2[3].x = DPPM(hv2[1].x, 0x141);    /* xor5  */                  \
            hv2[3].y = DPPM(hv2[1].y, 0x141);    /* xor4  */                  \
            hv2[4].x = DPPM(hv2[0].x, 0x140);    /* xor15 */                  \
            hv2[4].y = DPPM(hv2[0].y, 0x140);    /* xor14 */                  \
            hv2[5].x = DPPM(hv2[1].x, 0x140);    /* xor13 */                  \
            hv2[5].y = DPPM(hv2[1].y, 0x140);    /* xor12 */                  \
            hv2[6].x = DPPM(hv2[2].x, 0x140);    /* xor8  */                  \
            hv2[6].y = DPPM(hv2[2].y, 0x140);    /* xor9  */                  \
            hv2[7].x = DPPM(hv2[3].x, 0x140);    /* xor10 */                  \
            hv2[7].y = DPPM(hv2[3].y, 0x140);    /* xor11 */                  \
        }                                                                     \
    }

    const int Lfull = L & ~7;   // >= 8 since L >= 8

    // predicate-free main loop over full 8-step blocks
    for (int tb = 0; tb < Lfull; tb += 8) {
        #pragma unroll
        for (int i = 0; i < 8; ++i) {
            const int t = tb + i;
            const float xr = rg[i][0], xz = rg[i][1], xn = rg[i][2];
            {   // refill slot i for t+8 (clip; beyond-L garbage never consumed)
                int tl = t + 8; if (tl > TS - 1) tl = TS - 1;
                const float* p = gbase + (size_t)tl * G3;
                rg[i][0] = p[j]; rg[i][1] = p[32 + j]; rg[i][2] = p[64 + j];
            }
            GRU_STEP(xr, xz, xn, true)
        }
    }

    // predicated tail (< 8 steps); ring already holds t = Lfull..Lfull+7
    if (Lfull < L) {
        #pragma unroll
        for (int i = 0; i < 8; ++i) {
            const int t = Lfull + i;
            const float xr = rg[i][0], xz = rg[i][1], xn = rg[i][2];
            GRU_STEP(xr, xz, xn, (t < L))
        }
    }
    #undef GRU_STEP

    // every j counted twice (kh=0 and kh=1 lanes hold identical streams)
    #pragma unroll
    for (int off = 32; off > 0; off >>= 1) qacc += __shfl_xor(qacc, off, 64);
    if (lane == 0) out[n] = qacc * 0.5f / (float)L + bq;
}

// ---------------------------------------------------------------------------
extern "C" void kernel_launch(void* const* d_in, const int* in_sizes, int n_in,
                              void* d_out, int out_size, void* d_ws, size_t ws_size,
                              hipStream_t stream) {
    // setup_inputs order: x, fea, fea_len, W_ann, b_ann, W_ih, W_hh, b_ih, b_hh, W_q, b_q
    const float* fea   = (const float*)d_in[1];
    const int*   flen  = (const int*)  d_in[2];
    const float* W_ann = (const float*)d_in[3];
    const float* b_ann = (const float*)d_in[4];
    const float* W_ih  = (const float*)d_in[5];
    const float* W_hh  = (const float*)d_in[6];
    const float* b_ih  = (const float*)d_in[7];
    const float* b_hh  = (const float*)d_in[8];
    const float* W_q   = (const float*)d_in[9];
    const float* b_q   = (const float*)d_in[10];
    float* out = (float*)d_out;

    // ws layout: gx fp32 | Whi bf16 | Wlo bf16 | b_comb   (~13.4 MB total)
    float*          ws_f   = (float*)d_ws;
    float*          gx     = ws_f;
    unsigned short* Whi    = (unsigned short*)(ws_f + GX_FLOATS);
    unsigned short* Wlo    = Whi + W_ELEMS;
    float*          b_comb = (float*)(Wlo + W_ELEMS);

    k_prep<<<769, 256, 0, stream>>>(W_ann, b_ann, W_ih, b_ih, Whi, Wlo, b_comb);

    dim3 g2(NS, TS / 128);               // (32 samples, 8 t-tiles of 128)
    k_gemm<<<g2, 256, 0, stream>>>(fea, flen, Whi, Wlo, b_comb, gx);

    k_scan<<<NS, 64, 0, stream>>>(gx, flen, W_hh, b_hh, W_q, b_q, out);
}